// Round 10
// baseline (278.436 us; speedup 1.0000x reference)
//
#include <hip/hip_runtime.h>

#define NN 64
#define CC 128
#define TT 2048
#define SS 9
#define PAD 4
#define EPSF 1e-5f
#define TL 32                 // t columns per tile
#define NT 2                  // tiles per block in K1 (R7's verified depth)
#define TPB (NT * TL)         // 64
#define ROWS (CC + 2 * PAD)   // 136 staged rows
#define STRIDE 36             // 16B-aligned rows; bank-uniform (36%32=4)
#define NB 16                 // stat buckets

// ---------------------------------------------------------------------------
// R10: fp16 conv intermediate in WORKSPACE, TILE-MAJOR layout.
// R9's idea (K2 = pure stream) was right; its layout (fp16 inside fp32 rows)
// made K1's stores a 16B-granule scatter (41 us, 2.3 TB/s). Fix: workspace
// buffer hb[n][tile][jb_half][c][16] — each thread's 16 conv values are one
// contiguous 32B run; a wave stores 2 KB contiguous. K2 reads 32B-granule
// runs (256B contiguous per 8-lane group), normalizes via 1KB LDS g,b
// broadcast, writes fp32 out fully coalesced: the ~6.5 TB/s fill shape.
// Evidence ws is ~256 MiB (harness fill writes 262144 KB/iter); guarded by a
// host-side ws_size check with fallback to the verified R9 row-layout path.
// ---------------------------------------------------------------------------

union H8 { _Float16 h[8]; uint4 u; };
union H4 { _Float16 h[4]; uint2 u; };

__device__ __forceinline__ void tile_load(
    const float* __restrict__ xn, const int tb, const int tid,
    const bool interior, float4 (&v)[5])
{
#pragma unroll
    for (int p = 0; p < 5; ++p) {         // 136 rows x 8 lanes = 1088 slots
        const int f = tid + 256 * p;
        const int r = f >> 3;
        v[p] = make_float4(0.f, 0.f, 0.f, 0.f);
        if (r < ROWS) {
            const int c2 = r - PAD;
            if (c2 >= 0 && c2 < CC) {
                const int j0 = (f & 7) * 4;
                const int sh = c2 % SS - PAD;
                const int t  = tb + j0 - sh;              // 4B-aligned
                const float* __restrict__ row = xn + (size_t)c2 * TT;
                if (interior) {
                    __builtin_memcpy(&v[p], row + t, sizeof(float4));
                } else {
                    v[p].x = (t     >= 0 && t     < TT) ? row[t]     : 0.f;
                    v[p].y = (t + 1 >= 0 && t + 1 < TT) ? row[t + 1] : 0.f;
                    v[p].z = (t + 2 >= 0 && t + 2 < TT) ? row[t + 2] : 0.f;
                    v[p].w = (t + 3 >= 0 && t + 3 < TT) ? row[t + 3] : 0.f;
                }
            }
        }
    }
}

__device__ __forceinline__ void tile_write(
    float* __restrict__ ls, const int tid, const float4 (&v)[5])
{
#pragma unroll
    for (int p = 0; p < 5; ++p) {
        const int f = tid + 256 * p;
        const int r = f >> 3;
        if (r < ROWS)
            *reinterpret_cast<float4*>(&ls[r * STRIDE + (f & 7) * 4]) = v[p];
    }
}

__device__ __forceinline__ void conv_tile(
    const float* __restrict__ ls, const int base, const float (&wv)[SS],
    float (&res)[16])
{
#pragma unroll
    for (int j = 0; j < 16; ++j) res[j] = 0.f;
#pragma unroll
    for (int s = 0; s < SS; ++s) {
        const float4* rp = reinterpret_cast<const float4*>(&ls[base + s * STRIDE]);
        float4 r0 = rp[0], r1 = rp[1], r2 = rp[2], r3 = rp[3];
        const float w = wv[s];
        res[0]  = fmaf(w, r0.x, res[0]);  res[1]  = fmaf(w, r0.y, res[1]);
        res[2]  = fmaf(w, r0.z, res[2]);  res[3]  = fmaf(w, r0.w, res[3]);
        res[4]  = fmaf(w, r1.x, res[4]);  res[5]  = fmaf(w, r1.y, res[5]);
        res[6]  = fmaf(w, r1.z, res[6]);  res[7]  = fmaf(w, r1.w, res[7]);
        res[8]  = fmaf(w, r2.x, res[8]);  res[9]  = fmaf(w, r2.y, res[9]);
        res[10] = fmaf(w, r2.z, res[10]); res[11] = fmaf(w, r2.w, res[11]);
        res[12] = fmaf(w, r3.x, res[12]); res[13] = fmaf(w, r3.y, res[13]);
        res[14] = fmaf(w, r3.z, res[14]); res[15] = fmaf(w, r3.w, res[15]);
    }
}

// Store 16 fp32 -> 16 fp16 as one contiguous 32B run.
// fast: hb[tile_g][jb_half][c][16] (wave writes 2KB contiguous)
// slow: R9 row layout (verified fallback)
__device__ __forceinline__ void store_conv_f16(
    _Float16* __restrict__ hb, unsigned short* __restrict__ hrow,
    const int fast, const int tile_g, const int t0,
    const int c, const int jb, const float (&res)[16])
{
    H8 p0, p1;
#pragma unroll
    for (int j = 0; j < 8; ++j) {
        p0.h[j] = (_Float16)res[j];
        p1.h[j] = (_Float16)res[8 + j];
    }
    if (fast) {
        _Float16* dst = hb + (size_t)tile_g * (CC * TL)
                      + ((jb >> 4) * CC + c) * 16;
        *reinterpret_cast<uint4*>(dst)     = p0.u;
        *reinterpret_cast<uint4*>(dst + 8) = p1.u;
    } else {
        *reinterpret_cast<uint4*>(hrow + t0 + jb)     = p0.u;
        *reinterpret_cast<uint4*>(hrow + t0 + jb + 8) = p1.u;
    }
}

// K1: R7-structure pipelined conv -> stats atomics + coalesced fp16 store.
__global__ __launch_bounds__(256, 4) void conv_stats_f16(
    const float* __restrict__ x, const float* __restrict__ cw,
    float* __restrict__ buckets, _Float16* __restrict__ hb,
    float* __restrict__ out, const int fast)
{
    __shared__ float ls[ROWS * STRIDE];   // 19584 B

    const int n   = blockIdx.y;
    const int tA  = blockIdx.x * TPB;
    const int tB  = tA + TL;
    const int tid = threadIdx.x;
    const float* __restrict__ xn = x + (size_t)n * CC * TT;

    float4 va[5];
    tile_load(xn, tA, tid, blockIdx.x != 0, va);
    tile_write(ls, tid, va);

    const int c  = tid & (CC - 1);        // fixed output channel per thread
    const int jb = (tid >> 7) * (TL / 2); // 0 or 16
    float wv[SS];
#pragma unroll
    for (int s = 0; s < SS; ++s) wv[s] = cw[c * SS + s];
    unsigned short* __restrict__ hrow =
        reinterpret_cast<unsigned short*>(out + ((size_t)n * CC + c) * TT);
    const int gA = n * (TT / TL) + (tA >> 5);

    __syncthreads();                      // tile A staged

    float4 vb[5];                         // B loads in flight under conv A
    tile_load(xn, tB, tid, (int)blockIdx.x != (int)gridDim.x - 1, vb);

    const int base = c * STRIDE + jb;
    float res[16];
    conv_tile(ls, base, wv, res);
    float s1 = 0.f, s2 = 0.f;
#pragma unroll
    for (int j = 0; j < 16; ++j) { s1 += res[j]; s2 = fmaf(res[j], res[j], s2); }
    store_conv_f16(hb, hrow, fast, gA, tA, c, jb, res);

    __syncthreads();                      // conv A reads done
    tile_write(ls, tid, vb);
    __syncthreads();                      // tile B staged

    conv_tile(ls, base, wv, res);
#pragma unroll
    for (int j = 0; j < 16; ++j) { s1 += res[j]; s2 = fmaf(res[j], res[j], s2); }
    store_conv_f16(hb, hrow, fast, gA + 1, tB, c, jb, res);

    __syncthreads();                      // conv B reads done; ls reusable
    ls[tid]       = s1;
    ls[256 + tid] = s2;
    __syncthreads();
    if (tid < CC) {
        float* bs = buckets + ((blockIdx.x + blockIdx.y) & (NB - 1)) * 2 * CC;
        atomicAdd(&bs[tid],      ls[tid]       + ls[tid + 128]);
        atomicAdd(&bs[CC + tid], ls[256 + tid] + ls[256 + tid + 128]);
    }
}

// K2 (fast): pure stream. Fold -> g,b broadcast via 1KB LDS; read tile-major
// fp16 (32B-granule runs), normalize+ReLU, write fp32 out fully coalesced.
__global__ __launch_bounds__(256, 8) void norm_tile(
    const _Float16* __restrict__ hb, const float* __restrict__ buckets,
    const float* __restrict__ gamma, const float* __restrict__ beta,
    float* __restrict__ out)
{
    __shared__ float gs[CC], bs[CC];

    const int n   = blockIdx.y;
    const int tA  = blockIdx.x * TPB;
    const int tid = threadIdx.x;

    if (tid < CC) {                       // fold 16 L2-resident buckets
        float t1 = 0.f, t2 = 0.f;
#pragma unroll
        for (int k = 0; k < NB; ++k) {
            t1 += buckets[k * 2 * CC + tid];
            t2 += buckets[k * 2 * CC + CC + tid];
        }
        const float inv_cnt = 1.0f / (float)(NN * TT);
        const float mean = t1 * inv_cnt;
        const float var  = t2 * inv_cnt - mean * mean;
        const float inv  = rsqrtf(var + EPSF);
        const float g    = gamma[tid] * inv;
        gs[tid] = g;
        bs[tid] = beta[tid] - mean * g;
    }
    __syncthreads();

#pragma unroll
    for (int tile = 0; tile < NT; ++tile) {
        const int t0 = tA + tile * TL;
        const _Float16* __restrict__ tb =
            hb + (size_t)(n * (TT / TL) + (t0 >> 5)) * (CC * TL);
        float* __restrict__ on = out + (size_t)n * CC * TT + t0;
#pragma unroll
        for (int k = 0; k < 4; ++k) {     // 1024 float4 per tile
            const int f = tid + 256 * k;
            const int r = f >> 3;
            const int q = (f & 7) * 4;
            H4 h;
            h.u = *reinterpret_cast<const uint2*>(
                tb + ((q >> 4) * CC + r) * 16 + (q & 15));
            const float g = gs[r], b = bs[r];
            float4 v;
            v.x = fmaf((float)h.h[0], g, b);
            v.y = fmaf((float)h.h[1], g, b);
            v.z = fmaf((float)h.h[2], g, b);
            v.w = fmaf((float)h.h[3], g, b);
            v.x = v.x > 0.f ? v.x : 0.f;
            v.y = v.y > 0.f ? v.y : 0.f;
            v.z = v.z > 0.f ? v.z : 0.f;
            v.w = v.w > 0.f ? v.w : 0.f;
            *reinterpret_cast<float4*>(on + (size_t)r * TT + q) = v;
        }
    }
}

// K2 (fallback, verified R9): full-row blocks, fp16 in out rows, in-place.
__global__ __launch_bounds__(256, 8) void norm_relu_rows(
    const float* __restrict__ buckets, const float* __restrict__ gamma,
    const float* __restrict__ beta, float* __restrict__ out)
{
    const int r0  = blockIdx.x * 4;
    const int tid = threadIdx.x;

    float g[4], b[4];
#pragma unroll
    for (int k = 0; k < 4; ++k) {
        const int c = (r0 + k) & (CC - 1);
        float t1 = 0.f, t2 = 0.f;
#pragma unroll
        for (int kk = 0; kk < NB; ++kk) {
            t1 += buckets[kk * 2 * CC + c];
            t2 += buckets[kk * 2 * CC + CC + c];
        }
        const float inv_cnt = 1.0f / (float)(NN * TT);
        const float mean = t1 * inv_cnt;
        const float var  = t2 * inv_cnt - mean * mean;
        const float inv  = rsqrtf(var + EPSF);
        g[k] = gamma[c] * inv;
        b[k] = beta[c] - mean * g[k];
    }

    H8 hv[4];
#pragma unroll
    for (int k = 0; k < 4; ++k) {
        const unsigned short* hrow =
            reinterpret_cast<const unsigned short*>(out + (size_t)(r0 + k) * TT);
        hv[k].u = *reinterpret_cast<const uint4*>(hrow + 8 * tid);
    }
    __syncthreads();

#pragma unroll
    for (int k = 0; k < 4; ++k) {
        float4 lo, hi;
        lo.x = fmaf((float)hv[k].h[0], g[k], b[k]);
        lo.y = fmaf((float)hv[k].h[1], g[k], b[k]);
        lo.z = fmaf((float)hv[k].h[2], g[k], b[k]);
        lo.w = fmaf((float)hv[k].h[3], g[k], b[k]);
        hi.x = fmaf((float)hv[k].h[4], g[k], b[k]);
        hi.y = fmaf((float)hv[k].h[5], g[k], b[k]);
        hi.z = fmaf((float)hv[k].h[6], g[k], b[k]);
        hi.w = fmaf((float)hv[k].h[7], g[k], b[k]);
        lo.x = lo.x > 0.f ? lo.x : 0.f;
        lo.y = lo.y > 0.f ? lo.y : 0.f;
        lo.z = lo.z > 0.f ? lo.z : 0.f;
        lo.w = lo.w > 0.f ? lo.w : 0.f;
        hi.x = hi.x > 0.f ? hi.x : 0.f;
        hi.y = hi.y > 0.f ? hi.y : 0.f;
        hi.z = hi.z > 0.f ? hi.z : 0.f;
        hi.w = hi.w > 0.f ? hi.w : 0.f;
        float* row = out + (size_t)(r0 + k) * TT;
        *reinterpret_cast<float4*>(row + 8 * tid)     = lo;
        *reinterpret_cast<float4*>(row + 8 * tid + 4) = hi;
    }
}

extern "C" void kernel_launch(void* const* d_in, const int* in_sizes, int n_in,
                              void* d_out, int out_size, void* d_ws, size_t ws_size,
                              hipStream_t stream)
{
    const float* x     = (const float*)d_in[0];
    const float* cw    = (const float*)d_in[1];
    const float* gamma = (const float*)d_in[2];
    const float* beta  = (const float*)d_in[3];
    float* out     = (float*)d_out;
    float* buckets = (float*)d_ws;        // [NB][2][CC] = 16 KB

    const size_t bucket_bytes = (size_t)NB * 2 * CC * sizeof(float);
    const size_t hb_bytes     = (size_t)NN * CC * TT * sizeof(_Float16); // 32 MB
    const int fast = (ws_size >= bucket_bytes + hb_bytes) ? 1 : 0;
    _Float16* hb = (_Float16*)((char*)d_ws + bucket_bytes);

    hipMemsetAsync(buckets, 0, bucket_bytes, stream);

    dim3 grid1(TT / TPB, NN);             // 32 x 64 = 2048 blocks
    conv_stats_f16<<<grid1, 256, 0, stream>>>(x, cw, buckets, hb, out, fast);
    if (fast) {
        norm_tile<<<grid1, 256, 0, stream>>>(hb, buckets, gamma, beta, out);
    } else {
        norm_relu_rows<<<(NN * CC) / 4, 256, 0, stream>>>(buckets, gamma, beta, out);
    }
}

// Round 11
// 139.748 us; speedup vs baseline: 1.9924x; 1.9924x over previous
//
#include <hip/hip_runtime.h>

#define NN 64
#define CC 128
#define TT 2048
#define SS 9
#define PAD 4
#define EPSF 1e-5f
#define TL 32                 // t columns per tile
#define NT 2                  // tiles per block (R7's verified depth)
#define TPB (NT * TL)         // 64
#define ROWS (CC + 2 * PAD)   // 136 staged rows
#define STRIDE 36             // 16B-aligned rows; bank-uniform (36%32=4)
#define NB 16                 // stat buckets

// ---------------------------------------------------------------------------
// R11: fp16 conv intermediate (tile-major, coalesced), SPILL-PROOFED.
// R10 validated the layout + norm_tile correctness (passed, absmax 0.031) but
// its runtime fast/fallback dual-path store spilled (~330 MB scratch traffic,
// 180 us). Fix: single compiled path, no unions (fp16 pack/unpack via
// memcpy-to-int, stays in plain registers), K1 = verbatim R7 conv_stats
// (best-ever 141.7 us structure) + two uint4 stores per tile (wave writes
// 2 KB contiguous). K2 = pure stream: 32 MB fp16 in, 64 MB fp32 out.
// No-spill test in counters: K1 WRITE_SIZE must be ~33-40 MB.
// ---------------------------------------------------------------------------

__device__ __forceinline__ unsigned int f2h2(float a, float b)
{
    _Float16 ha = (_Float16)a, hb = (_Float16)b;
    unsigned short ua, ub;
    __builtin_memcpy(&ua, &ha, 2);
    __builtin_memcpy(&ub, &hb, 2);
    return (unsigned int)ua | ((unsigned int)ub << 16);
}

__device__ __forceinline__ float h2f_lo(unsigned int w)
{
    unsigned short u = (unsigned short)(w & 0xffffu);
    _Float16 h;
    __builtin_memcpy(&h, &u, 2);
    return (float)h;
}

__device__ __forceinline__ float h2f_hi(unsigned int w)
{
    unsigned short u = (unsigned short)(w >> 16);
    _Float16 h;
    __builtin_memcpy(&h, &u, 2);
    return (float)h;
}

__device__ __forceinline__ void tile_load(
    const float* __restrict__ xn, const int tb, const int tid,
    const bool interior, float4 (&v)[5])
{
#pragma unroll
    for (int p = 0; p < 5; ++p) {         // 136 rows x 8 lanes = 1088 slots
        const int f = tid + 256 * p;
        const int r = f >> 3;
        v[p] = make_float4(0.f, 0.f, 0.f, 0.f);
        if (r < ROWS) {
            const int c2 = r - PAD;
            if (c2 >= 0 && c2 < CC) {
                const int j0 = (f & 7) * 4;
                const int sh = c2 % SS - PAD;
                const int t  = tb + j0 - sh;              // 4B-aligned
                const float* __restrict__ row = xn + (size_t)c2 * TT;
                if (interior) {
                    __builtin_memcpy(&v[p], row + t, sizeof(float4));
                } else {
                    v[p].x = (t     >= 0 && t     < TT) ? row[t]     : 0.f;
                    v[p].y = (t + 1 >= 0 && t + 1 < TT) ? row[t + 1] : 0.f;
                    v[p].z = (t + 2 >= 0 && t + 2 < TT) ? row[t + 2] : 0.f;
                    v[p].w = (t + 3 >= 0 && t + 3 < TT) ? row[t + 3] : 0.f;
                }
            }
        }
    }
}

__device__ __forceinline__ void tile_write(
    float* __restrict__ ls, const int tid, const float4 (&v)[5])
{
#pragma unroll
    for (int p = 0; p < 5; ++p) {
        const int f = tid + 256 * p;
        const int r = f >> 3;
        if (r < ROWS)
            *reinterpret_cast<float4*>(&ls[r * STRIDE + (f & 7) * 4]) = v[p];
    }
}

__device__ __forceinline__ void conv_tile(
    const float* __restrict__ ls, const int base, const float (&wv)[SS],
    float (&res)[16])
{
#pragma unroll
    for (int j = 0; j < 16; ++j) res[j] = 0.f;
#pragma unroll
    for (int s = 0; s < SS; ++s) {
        const float4* rp = reinterpret_cast<const float4*>(&ls[base + s * STRIDE]);
        float4 r0 = rp[0], r1 = rp[1], r2 = rp[2], r3 = rp[3];
        const float w = wv[s];
        res[0]  = fmaf(w, r0.x, res[0]);  res[1]  = fmaf(w, r0.y, res[1]);
        res[2]  = fmaf(w, r0.z, res[2]);  res[3]  = fmaf(w, r0.w, res[3]);
        res[4]  = fmaf(w, r1.x, res[4]);  res[5]  = fmaf(w, r1.y, res[5]);
        res[6]  = fmaf(w, r1.z, res[6]);  res[7]  = fmaf(w, r1.w, res[7]);
        res[8]  = fmaf(w, r2.x, res[8]);  res[9]  = fmaf(w, r2.y, res[9]);
        res[10] = fmaf(w, r2.z, res[10]); res[11] = fmaf(w, r2.w, res[11]);
        res[12] = fmaf(w, r3.x, res[12]); res[13] = fmaf(w, r3.y, res[13]);
        res[14] = fmaf(w, r3.z, res[14]); res[15] = fmaf(w, r3.w, res[15]);
    }
}

// pack 16 fp32 -> 16 fp16, store as one contiguous 32B run (two uint4).
// layout: hb32[tile_g][jb_half][c][8 uints]; a wave writes 2KB contiguous.
__device__ __forceinline__ void store_conv_f16(
    unsigned int* __restrict__ hb32, const int tile_g,
    const int c, const int jb, const float (&res)[16])
{
    uint4 p0, p1;
    p0.x = f2h2(res[0],  res[1]);  p0.y = f2h2(res[2],  res[3]);
    p0.z = f2h2(res[4],  res[5]);  p0.w = f2h2(res[6],  res[7]);
    p1.x = f2h2(res[8],  res[9]);  p1.y = f2h2(res[10], res[11]);
    p1.z = f2h2(res[12], res[13]); p1.w = f2h2(res[14], res[15]);
    unsigned int* dst = hb32 + (size_t)tile_g * (CC * TL / 2)
                      + ((jb >> 4) * CC + c) * 8;
    *reinterpret_cast<uint4*>(dst)     = p0;
    *reinterpret_cast<uint4*>(dst + 4) = p1;
}

// K1: verbatim R7 pipelined conv+stats + coalesced fp16 tile-major stores.
__global__ __launch_bounds__(256, 4) void conv_stats_f16(
    const float* __restrict__ x, const float* __restrict__ cw,
    float* __restrict__ buckets, unsigned int* __restrict__ hb32)
{
    __shared__ float ls[ROWS * STRIDE];   // 19584 B

    const int n   = blockIdx.y;
    const int tA  = blockIdx.x * TPB;
    const int tB  = tA + TL;
    const int tid = threadIdx.x;
    const float* __restrict__ xn = x + (size_t)n * CC * TT;

    float4 va[5];
    tile_load(xn, tA, tid, blockIdx.x != 0, va);
    tile_write(ls, tid, va);

    const int c  = tid & (CC - 1);        // fixed output channel per thread
    const int jb = (tid >> 7) * (TL / 2); // 0 or 16
    float wv[SS];
#pragma unroll
    for (int s = 0; s < SS; ++s) wv[s] = cw[c * SS + s];
    const int gA = n * (TT / TL) + (tA >> 5);

    __syncthreads();                      // tile A staged

    float4 vb[5];                         // B loads in flight under conv A
    tile_load(xn, tB, tid, (int)blockIdx.x != (int)gridDim.x - 1, vb);

    const int base = c * STRIDE + jb;
    float res[16];
    conv_tile(ls, base, wv, res);
    float s1 = 0.f, s2 = 0.f;
#pragma unroll
    for (int j = 0; j < 16; ++j) { s1 += res[j]; s2 = fmaf(res[j], res[j], s2); }
    store_conv_f16(hb32, gA, c, jb, res); // fire-and-forget, coalesced

    __syncthreads();                      // conv A reads done
    tile_write(ls, tid, vb);
    __syncthreads();                      // tile B staged

    conv_tile(ls, base, wv, res);
#pragma unroll
    for (int j = 0; j < 16; ++j) { s1 += res[j]; s2 = fmaf(res[j], res[j], s2); }
    store_conv_f16(hb32, gA + 1, c, jb, res);

    __syncthreads();                      // conv B reads done; ls reusable
    ls[tid]       = s1;
    ls[256 + tid] = s2;
    __syncthreads();
    if (tid < CC) {
        float* bs = buckets + ((blockIdx.x + blockIdx.y) & (NB - 1)) * 2 * CC;
        atomicAdd(&bs[tid],      ls[tid]       + ls[tid + 128]);
        atomicAdd(&bs[CC + tid], ls[256 + tid] + ls[256 + tid + 128]);
    }
}

// K2: pure stream. Fold buckets -> g,b via 1KB LDS broadcast; read tile-major
// fp16 (uint2 = 4 halves per load), normalize+ReLU, write fp32 coalesced.
__global__ __launch_bounds__(256, 8) void norm_tile(
    const unsigned int* __restrict__ hb32, const float* __restrict__ buckets,
    const float* __restrict__ gamma, const float* __restrict__ beta,
    float* __restrict__ out)
{
    __shared__ float gs[CC], bs[CC];

    const int n   = blockIdx.y;
    const int tA  = blockIdx.x * TPB;
    const int tid = threadIdx.x;

    if (tid < CC) {                       // fold 16 L2-resident buckets
        float t1 = 0.f, t2 = 0.f;
#pragma unroll
        for (int k = 0; k < NB; ++k) {
            t1 += buckets[k * 2 * CC + tid];
            t2 += buckets[k * 2 * CC + CC + tid];
        }
        const float inv_cnt = 1.0f / (float)(NN * TT);
        const float mean = t1 * inv_cnt;
        const float var  = t2 * inv_cnt - mean * mean;
        const float inv  = rsqrtf(var + EPSF);
        const float g    = gamma[tid] * inv;
        gs[tid] = g;
        bs[tid] = beta[tid] - mean * g;
    }
    __syncthreads();

#pragma unroll
    for (int tile = 0; tile < NT; ++tile) {
        const int t0 = tA + tile * TL;
        const unsigned int* __restrict__ tb =
            hb32 + (size_t)(n * (TT / TL) + (t0 >> 5)) * (CC * TL / 2);
        float* __restrict__ on = out + (size_t)n * CC * TT + t0;
#pragma unroll
        for (int k = 0; k < 4; ++k) {     // 1024 float4 per tile
            const int f = tid + 256 * k;
            const int r = f >> 3;
            const int q = (f & 7) * 4;    // 0,4,...,28
            const unsigned int* src =
                tb + ((q >> 4) * CC + r) * 8 + ((q & 15) >> 1);
            const unsigned int w0 = src[0];
            const unsigned int w1 = src[1];
            const float g = gs[r], b = bs[r];
            float4 v;
            v.x = fmaf(h2f_lo(w0), g, b);
            v.y = fmaf(h2f_hi(w0), g, b);
            v.z = fmaf(h2f_lo(w1), g, b);
            v.w = fmaf(h2f_hi(w1), g, b);
            v.x = v.x > 0.f ? v.x : 0.f;
            v.y = v.y > 0.f ? v.y : 0.f;
            v.z = v.z > 0.f ? v.z : 0.f;
            v.w = v.w > 0.f ? v.w : 0.f;
            *reinterpret_cast<float4*>(on + (size_t)r * TT + q) = v;
        }
    }
}

extern "C" void kernel_launch(void* const* d_in, const int* in_sizes, int n_in,
                              void* d_out, int out_size, void* d_ws, size_t ws_size,
                              hipStream_t stream)
{
    const float* x     = (const float*)d_in[0];
    const float* cw    = (const float*)d_in[1];
    const float* gamma = (const float*)d_in[2];
    const float* beta  = (const float*)d_in[3];
    float* out     = (float*)d_out;
    float* buckets = (float*)d_ws;        // [NB][2][CC] = 16 KB

    const size_t bucket_bytes = (size_t)NB * 2 * CC * sizeof(float);
    unsigned int* hb32 = (unsigned int*)((char*)d_ws + bucket_bytes); // 32 MB

    hipMemsetAsync(buckets, 0, bucket_bytes, stream);

    dim3 grid1(TT / TPB, NN);             // 32 x 64 = 2048 blocks
    conv_stats_f16<<<grid1, 256, 0, stream>>>(x, cw, buckets, hb32);
    norm_tile<<<grid1, 256, 0, stream>>>(hb32, buckets, gamma, beta, out);
}